// Round 2
// baseline (43046.915 us; speedup 1.0000x reference)
//
#include <hip/hip_runtime.h>
#include <math.h>

// ---------------------------------------------------------------------------
// 2-layer bidirectional LSTM, variational dropout, fp32.
// One launch per (layer, step); grid 256 WGs x 256 thr.
// WG g -> cell = layer*2 + (g>>7), hidden units u0=4*(g&127) (16 gate cols).
// Per chunk (CHK=64 of K): prefetch globals AFTER barrier (loads fly over
// compute), double-buffered LDS, 4x4 fp32 register tile per lane.
// h stored pre-masked+transposed in hmT[cell][unit][b] for contiguous staging.
// ---------------------------------------------------------------------------

#define SLEN   512
#define HID    512
#define CHK    64
#define APAD   68                         // padded LDS row stride (floats)
#define OUT_SEQ  (SLEN*64*2*HID)          // 33,554,432 floats
#define STATE_SZ (4*64*HID)               // 131,072 floats

__global__ __launch_bounds__(256) void zero_hm(float* __restrict__ hmT) {
    *(float4*)(hmT + (blockIdx.x*256 + threadIdx.x)*4) =
        make_float4(0.f, 0.f, 0.f, 0.f);
}

template<int LAYER>
__global__ __launch_bounds__(256) void lstm_step(
    const float* __restrict__ x,      // [512,64,512]
    const float* __restrict__ Wih0,   // [2,2048,512]
    const float* __restrict__ Wih1,   // [2,2048,1024]
    const float* __restrict__ Whh,    // [4,2048,512]
    const float* __restrict__ bih,    // [4,2048]
    const float* __restrict__ bhh,    // [4,2048]
    const float* __restrict__ mx0,    // [2,64,512]
    const float* __restrict__ mx1,    // [2,64,1024]
    const float* __restrict__ mhm,    // [4,64,512]
    float* __restrict__ out0,         // ws: [512,64,1024] layer-0 output
    float* __restrict__ hmT,          // ws: [4,512,64]  h*mh, transposed
    float* __restrict__ cst,          // ws: [4,64,512]  cell state
    float* __restrict__ dout,         // [S,B,1024] ++ hn[4,64,512] ++ cn[4,64,512]
    int s)
{
    constexpr int Kin = LAYER ? 1024 : 512;
    constexpr int NCH = (Kin + HID)/CHK;       // 16 (L0) or 24 (L1)

    __shared__ __align__(16) float At[2][CHK*APAD];   // 2 x 17.4 KB
    __shared__ __align__(16) float Wt[2][CHK*16];     // 2 x 4 KB

    const int g    = blockIdx.x;
    const int dir  = g >> 7;
    const int wg   = g & 127;
    const int cell = LAYER*2 + dir;
    const int t    = dir ? (SLEN-1-s) : s;
    const int u0   = wg*4;
    const int tid  = threadIdx.x;
    const int lane = tid & 63;
    const int wv   = tid >> 6;

    // compute-phase 4x4 tile coords
    const int r0 = (lane & 15)*4;              // batch rows
    const int c0 = (lane >> 4)*4;              // local gate cols

    // A staging (x-part: transpose; lane k-interleaved for 2-way banks)
    const int sb = tid >> 2;                   // batch row 0..63
    const int ak = (tid & 3)*4;                // k sub-offset (+ q*16)
    // A staging (h-part: direct rows from hmT)
    const int hr = tid >> 4;                   // row 0..15 (+ q*16)
    const int hb = (tid & 15)*4;               // b offset
    // W staging (XOR block-swizzled cols)
    const int wc   = tid >> 4;                 // logical col 0..15
    const int wko  = (tid & 15)*4;             // k block of 4
    const int wkey = ((tid & 15) >> 1) & 3;    // (k>>3)&3 for this thread's k
    const int wpc  = (((wc >> 2) ^ wkey) << 2) | (wc & 3);   // physical col
    const int gcw  = (wc >> 2)*512 + u0 + (wc & 3);          // global gate row

    // compute-side W physical col-block bases (swizzle key per 8-k group)
    const int pbA = (((c0 >> 2) ^ ((wv*2    ) & 3)) << 2);
    const int pbB = (((c0 >> 2) ^ ((wv*2 + 1) & 3)) << 2);

    float acc[4][4];
#pragma unroll
    for (int i = 0; i < 4; ++i)
#pragma unroll
        for (int j = 0; j < 4; ++j) acc[i][j] = 0.0f;

    float4 va0, va1, va2, va3, vm0, vm1, vm2, vm3, w4;
    bool xpart = true;

    auto prefetch = [&](int ch) {
        const int k0 = ch*CHK;
        xpart = (k0 < Kin);
        if (xpart) {
            const float *asrc, *amsk, *wsrc;
            if (LAYER == 0) {
                asrc = x   + ((size_t)(t*64   + sb))*512  + k0 + ak;
                amsk = mx0 + ((size_t)(dir*64 + sb))*512  + k0 + ak;
                wsrc = Wih0 + (size_t)dir*2048*512  + (size_t)gcw*512  + k0 + wko;
            } else {
                asrc = out0 + ((size_t)(t*64   + sb))*1024 + k0 + ak;
                amsk = mx1  + ((size_t)(dir*64 + sb))*1024 + k0 + ak;
                wsrc = Wih1 + (size_t)dir*2048*1024 + (size_t)gcw*1024 + k0 + wko;
            }
            va0 = *(const float4*)(asrc);      vm0 = *(const float4*)(amsk);
            va1 = *(const float4*)(asrc + 16); vm1 = *(const float4*)(amsk + 16);
            va2 = *(const float4*)(asrc + 32); vm2 = *(const float4*)(amsk + 32);
            va3 = *(const float4*)(asrc + 48); vm3 = *(const float4*)(amsk + 48);
            w4  = *(const float4*)(wsrc);
        } else {
            const int kh = k0 - Kin;
            const float* hsrc = hmT + ((size_t)(cell*512 + kh + hr))*64 + hb;
            va0 = *(const float4*)(hsrc);
            va1 = *(const float4*)(hsrc + 16*64);
            va2 = *(const float4*)(hsrc + 32*64);
            va3 = *(const float4*)(hsrc + 48*64);
            w4  = *(const float4*)(Whh + (size_t)cell*2048*512
                                       + (size_t)gcw*512 + kh + wko);
        }
    };

    auto writeb = [&](float* Ab, float* Wb) {
        if (xpart) {
#define WRQ(Q, V, M)  { \
            Ab[(ak + (Q)*16 + 0)*APAD + sb] = V.x*M.x; \
            Ab[(ak + (Q)*16 + 1)*APAD + sb] = V.y*M.y; \
            Ab[(ak + (Q)*16 + 2)*APAD + sb] = V.z*M.z; \
            Ab[(ak + (Q)*16 + 3)*APAD + sb] = V.w*M.w; }
            WRQ(0, va0, vm0) WRQ(1, va1, vm1) WRQ(2, va2, vm2) WRQ(3, va3, vm3)
#undef WRQ
        } else {
            *(float4*)(Ab + (hr +  0)*APAD + hb) = va0;
            *(float4*)(Ab + (hr + 16)*APAD + hb) = va1;
            *(float4*)(Ab + (hr + 32)*APAD + hb) = va2;
            *(float4*)(Ab + (hr + 48)*APAD + hb) = va3;
        }
        Wb[(wko+0)*16 + wpc] = w4.x;
        Wb[(wko+1)*16 + wpc] = w4.y;
        Wb[(wko+2)*16 + wpc] = w4.z;
        Wb[(wko+3)*16 + wpc] = w4.w;
    };

    auto compute = [&](const float* Ab, const float* Wb) {
#pragma unroll
        for (int kk = 0; kk < 16; ++kk) {
            const int krow = wv*16 + kk;
            const float4 a = *(const float4*)(Ab + krow*APAD + r0);
            const float4 w = *(const float4*)(Wb + krow*16 + (kk < 8 ? pbA : pbB));
            acc[0][0] += a.x*w.x; acc[0][1] += a.x*w.y; acc[0][2] += a.x*w.z; acc[0][3] += a.x*w.w;
            acc[1][0] += a.y*w.x; acc[1][1] += a.y*w.y; acc[1][2] += a.y*w.z; acc[1][3] += a.y*w.w;
            acc[2][0] += a.z*w.x; acc[2][1] += a.z*w.y; acc[2][2] += a.z*w.z; acc[2][3] += a.z*w.w;
            acc[3][0] += a.w*w.x; acc[3][1] += a.w*w.y; acc[3][2] += a.w*w.z; acc[3][3] += a.w*w.w;
        }
    };

    // -------- pipelined K loop: sync -> prefetch(next) -> compute -> write ---
    prefetch(0);
    writeb(At[0], Wt[0]);
    for (int ch = 0; ch < NCH; ++ch) {
        __syncthreads();
        const int p = ch & 1;
        if (ch + 1 < NCH) prefetch(ch + 1);      // issued AFTER barrier: in
        compute(At[p], Wt[p]);                   // flight across compute
        if (ch + 1 < NCH) writeb(At[p^1], Wt[p^1]);
    }

    // -------- cross-wave reduce: red[wv][c][b] in At[0] (safe: synced) ------
    float* red = At[0];
#pragma unroll
    for (int j = 0; j < 4; ++j)
        *(float4*)(red + wv*1024 + (c0+j)*64 + r0) =
            make_float4(acc[0][j], acc[1][j], acc[2][j], acc[3][j]);
    __syncthreads();

    // -------- elementwise: thread -> (batch b, unit u0+u) -------------------
    {
        const int b = tid & 63;
        const int u = tid >> 6;
        float gq[4];
#pragma unroll
        for (int q = 0; q < 4; ++q) {
            const int c = q*4 + u;
            float v = red[c*64 + b] + red[1024 + c*64 + b]
                    + red[2048 + c*64 + b] + red[3072 + c*64 + b];
            const int gc = q*512 + u0 + u;
            v += bih[cell*2048 + gc] + bhh[cell*2048 + gc];
            gq[q] = v;
        }
        const size_t sidx = ((size_t)(cell*64 + b))*512 + u0 + u;
        const float cprev = (s > 0) ? cst[sidx] : 0.0f;
        const float ig = 1.0f/(1.0f + expf(-gq[0]));
        const float fg = 1.0f/(1.0f + expf(-gq[1]));
        const float gg = tanhf(gq[2]);
        const float og = 1.0f/(1.0f + expf(-gq[3]));
        const float cnew = fg*cprev + ig*gg;
        const float hnew = og*tanhf(cnew);
        cst[sidx] = cnew;
        hmT[((size_t)(cell*512 + u0 + u))*64 + b] = hnew * mhm[sidx];
        float* obase = LAYER ? dout : out0;
        obase[((size_t)(t*64 + b))*1024 + dir*512 + u0 + u] = hnew;
        if (s == SLEN-1) {
            dout[OUT_SEQ + sidx]            = hnew;   // h_n
            dout[OUT_SEQ + STATE_SZ + sidx] = cnew;   // c_n
        }
    }
}

extern "C" void kernel_launch(void* const* d_in, const int* in_sizes, int n_in,
                              void* d_out, int out_size, void* d_ws, size_t ws_size,
                              hipStream_t stream)
{
    const float* x    = (const float*)d_in[0];
    const float* Wih0 = (const float*)d_in[1];
    const float* Wih1 = (const float*)d_in[2];
    const float* Whh  = (const float*)d_in[3];
    const float* bih  = (const float*)d_in[4];
    const float* bhh  = (const float*)d_in[5];
    const float* mx0  = (const float*)d_in[6];
    const float* mx1  = (const float*)d_in[7];
    const float* mhm  = (const float*)d_in[8];

    float* out  = (float*)d_out;
    float* out0 = (float*)d_ws;                 // [512,64,1024]
    float* hmT  = out0 + OUT_SEQ;               // [4,512,64]  (h * mask_h)^T
    float* cst  = hmT + STATE_SZ;               // [4,64,512]

    zero_hm<<<128, 256, 0, stream>>>(hmT);      // h0 = 0 (ws is poisoned)

    for (int s = 0; s < SLEN; ++s)
        lstm_step<0><<<256, 256, 0, stream>>>(x, Wih0, Wih1, Whh, bih, bhh,
                                              mx0, mx1, mhm, out0, hmT, cst, out, s);
    for (int s = 0; s < SLEN; ++s)
        lstm_step<1><<<256, 256, 0, stream>>>(x, Wih0, Wih1, Whh, bih, bhh,
                                              mx0, mx1, mhm, out0, hmT, cst, out, s);
}